// Round 3
// baseline (773.567 us; speedup 1.0000x reference)
//
#include <hip/hip_runtime.h>
#include <hip/hip_bf16.h>
#include <stdint.h>

// ---------------------------------------------------------------------------
// InvariantPointAttention, B=1 N=768 CS=384 CZ=128 CH=16 H=12 PQ=4 PV=8
// weight = softmax over size-1 axis == 1.0  =>  _mix(x) == x[:,:,0] (frame 0).
//
// K0 k_init     : out = bout (broadcast) -- target of k_gemm atomics
// K1 k_se_gemm  : se_raw = s @ wexp[0:384].T + bexp   (32x32 fp32 tiles)
// K2 k_ln       : se0 = LN(se_raw) * g + b
// K3 k_proj_gemm: lin = se0 @ [wq;wkv;wqp;wkvp].T + bias (32x32 fp32 tiles)
// K4 k_post     : split q/k/v, rotate points, bf16 casts, K2 = sum k_pts^2
// K5 k_attn     : flash attention, j-split S=2 -> unnormalized partials
// K6 k_attn_fin : merge 2 partials (exp-weights), rotation epilogue -> cat
// K7 k_gemm     : out += cat @ wout.T (fp32, split-K=12, atomicAdd)
// ---------------------------------------------------------------------------

typedef float  f32x4 __attribute__((ext_vector_type(4)));
typedef float  f32x2 __attribute__((ext_vector_type(2)));
typedef short  s16x8 __attribute__((ext_vector_type(8)));

__device__ __forceinline__ float bf2f(unsigned short u) {
    union { unsigned int i; float f; } v; v.i = ((unsigned int)u) << 16; return v.f;
}
__device__ __forceinline__ unsigned short f2bf(float f) {
    union { float f; unsigned int i; } v; v.f = f;
    unsigned int r = v.i + 0x7fffu + ((v.i >> 16) & 1u);
    return (unsigned short)(r >> 16);
}
__device__ __forceinline__ unsigned packbf2(float a, float b) {
    return (unsigned)f2bf(a) | ((unsigned)f2bf(b) << 16);
}

// ------------------------------- K0: init out with bias --------------------
__global__ __launch_bounds__(256) void k_init(
    const float* __restrict__ bout, float* __restrict__ out)
{
    const int x = blockIdx.x * 256 + threadIdx.x;    // < 294912
    out[x] = bout[x % 384];
}

// ------------------------------- K1: se_raw GEMM (32x32) -------------------
__global__ __launch_bounds__(256) void k_se_gemm(
    const float* __restrict__ s, const float* __restrict__ wexp,
    const float* __restrict__ bexp, float* __restrict__ se_raw)
{
    const int m0 = blockIdx.x * 32, n0 = blockIdx.y * 32;
    const int t = threadIdx.x, tx = t & 15, ty = t >> 4;
    __shared__ float Sl[32 * 34];
    __shared__ float Wl[32 * 34];
    const int lrow = t >> 3, lk4 = (t & 7) * 4;
    const float* sp = s    + (size_t)(m0 + lrow) * 384;
    const float* wp = wexp + (size_t)(n0 + lrow) * 384;
    float acc[2][2] = {};

    for (int kc = 0; kc < 12; ++kc) {
        const int k0 = kc * 32;
        __syncthreads();
        f32x4 sv = *(const f32x4*)(sp + k0 + lk4);
        f32x4 wv = *(const f32x4*)(wp + k0 + lk4);
        #pragma unroll
        for (int ii = 0; ii < 4; ++ii) {
            Sl[(lk4 + ii) * 34 + lrow] = sv[ii];
            Wl[(lk4 + ii) * 34 + lrow] = wv[ii];
        }
        __syncthreads();
        #pragma unroll
        for (int kk = 0; kk < 32; ++kk) {
            f32x2 a = *(const f32x2*)&Sl[kk * 34 + ty * 2];
            f32x2 b = *(const f32x2*)&Wl[kk * 34 + tx * 2];
            acc[0][0] += a[0] * b[0]; acc[0][1] += a[0] * b[1];
            acc[1][0] += a[1] * b[0]; acc[1][1] += a[1] * b[1];
        }
    }
    f32x2 bb = *(const f32x2*)(bexp + n0 + tx * 2);
    #pragma unroll
    for (int r = 0; r < 2; ++r) {
        f32x2 v = { acc[r][0] + bb[0], acc[r][1] + bb[1] };
        *(f32x2*)(se_raw + (size_t)(m0 + ty * 2 + r) * 384 + n0 + tx * 2) = v;
    }
}

// ------------------------------- K2: LayerNorm -----------------------------
__global__ __launch_bounds__(256) void k_ln(
    const float* __restrict__ se_raw, const float* __restrict__ ln_g,
    const float* __restrict__ ln_b, float* __restrict__ se0)
{
    const int n = blockIdx.x * 4 + (threadIdx.x >> 6);
    const int lane = threadIdx.x & 63;
    const float* row = se_raw + (size_t)n * 384;
    float v[6], s1 = 0.f, s2 = 0.f;
    #pragma unroll
    for (int q = 0; q < 6; ++q) {
        v[q] = row[lane + q * 64];
        s1 += v[q]; s2 += v[q] * v[q];
    }
    for (int mk = 1; mk < 64; mk <<= 1) {
        s1 += __shfl_xor(s1, mk, 64);
        s2 += __shfl_xor(s2, mk, 64);
    }
    float mu = s1 * (1.f / 384.f);
    float var = s2 * (1.f / 384.f) - mu * mu;
    float rs = rsqrtf(fmaxf(var, 0.f) + 1e-5f);
    float* orow = se0 + (size_t)n * 384;
    #pragma unroll
    for (int q = 0; q < 6; ++q) {
        int c = lane + q * 64;
        orow[c] = (v[q] - mu) * rs * ln_g[c] + ln_b[c];
    }
}

// ------------------------------- K3: projection GEMM (32x32) ---------------
__device__ __forceinline__ const float* wrow(int c,
    const float* wq, const float* wkv, const float* wqp, const float* wkvp)
{
    if (c < 192)      return wq   + (size_t)c * 384;
    else if (c < 576) return wkv  + (size_t)(c - 192) * 384;
    else if (c < 720) return wqp  + (size_t)(c - 576) * 384;
    else              return wkvp + (size_t)(c - 720) * 384;
}
__device__ __forceinline__ float bval(int c,
    const float* bq, const float* bkv, const float* bqp, const float* bkvp)
{
    if (c < 192)      return bq[c];
    else if (c < 576) return bkv[c - 192];
    else if (c < 720) return bqp[c - 576];
    else              return bkvp[c - 720];
}

__global__ __launch_bounds__(256) void k_proj_gemm(
    const float* __restrict__ se0,
    const float* __restrict__ wq,  const float* __restrict__ bq,
    const float* __restrict__ wkv, const float* __restrict__ bkv,
    const float* __restrict__ wqp, const float* __restrict__ bqp,
    const float* __restrict__ wkvp,const float* __restrict__ bkvp,
    float* __restrict__ lin)
{
    const int m0 = blockIdx.x * 32, n0 = blockIdx.y * 32;
    const int t = threadIdx.x, tx = t & 15, ty = t >> 4;
    __shared__ float Sl[32 * 34];
    __shared__ float Wl[32 * 34];
    const int lrow = t >> 3, lk4 = (t & 7) * 4;
    const float* sp = se0 + (size_t)(m0 + lrow) * 384;
    const float* wp = wrow(n0 + lrow, wq, wkv, wqp, wkvp);
    float acc[2][2] = {};

    for (int kc = 0; kc < 12; ++kc) {
        const int k0 = kc * 32;
        __syncthreads();
        f32x4 sv = *(const f32x4*)(sp + k0 + lk4);
        f32x4 wv = *(const f32x4*)(wp + k0 + lk4);
        #pragma unroll
        for (int ii = 0; ii < 4; ++ii) {
            Sl[(lk4 + ii) * 34 + lrow] = sv[ii];
            Wl[(lk4 + ii) * 34 + lrow] = wv[ii];
        }
        __syncthreads();
        #pragma unroll
        for (int kk = 0; kk < 32; ++kk) {
            f32x2 a = *(const f32x2*)&Sl[kk * 34 + ty * 2];
            f32x2 b = *(const f32x2*)&Wl[kk * 34 + tx * 2];
            acc[0][0] += a[0] * b[0]; acc[0][1] += a[0] * b[1];
            acc[1][0] += a[1] * b[0]; acc[1][1] += a[1] * b[1];
        }
    }
    float b0 = bval(n0 + tx * 2,     bq, bkv, bqp, bkvp);
    float b1 = bval(n0 + tx * 2 + 1, bq, bkv, bqp, bkvp);
    #pragma unroll
    for (int r = 0; r < 2; ++r) {
        f32x2 v = { acc[r][0] + b0, acc[r][1] + b1 };
        *(f32x2*)(lin + (size_t)(m0 + ty * 2 + r) * 1152 + n0 + tx * 2) = v;
    }
}

// ------------------------------- K4: post-process --------------------------
__global__ __launch_bounds__(256) void k_post(
    const float* __restrict__ lin,
    const float* __restrict__ r_rot, const float* __restrict__ r_trans,
    float* __restrict__ q_out, unsigned short* __restrict__ k_out,
    unsigned short* __restrict__ v_out, float* __restrict__ qp_out,
    unsigned short* __restrict__ kp_out, unsigned short* __restrict__ vp_out,
    float* __restrict__ k2_out)
{
    const int n0 = blockIdx.x * 8;
    const int t = threadIdx.x;
    __shared__ float kprot[8 * 144];

    for (int r = 0; r < 8; ++r) {
        const int n = n0 + r;
        const float* lrow = lin + (size_t)n * 1152;
        const float* rot = r_rot + (size_t)n * 45;        // frame 0
        for (int u = t; u < 1152; u += 256) {
            if (u < 192) {
                q_out[(size_t)n * 192 + u] = lrow[u];
            } else if (u < 576) {
                int l2 = u - 192, h = l2 >> 5, c = l2 & 31;
                float v = lrow[u];
                if (c < 16) k_out[(size_t)n * 192 + h * 16 + c] = f2bf(v);
                else        v_out[(size_t)n * 192 + h * 16 + (c - 16)] = f2bf(v);
            } else {
                int y = u - 576;
                int pt = y / 3, i = y - pt * 3;
                float t0 = r_trans[(size_t)n * 15 + i];
                float v;
                if (pt < 48) {
                    v = rot[i*3+0] * lrow[576 + pt]
                      + rot[i*3+1] * lrow[576 + 48 + pt]
                      + rot[i*3+2] * lrow[576 + 96 + pt] + t0;
                    qp_out[(size_t)n * 144 + pt * 3 + i] = v;
                } else {
                    int pp = pt - 48;
                    v = rot[i*3+0] * lrow[720 + pp]
                      + rot[i*3+1] * lrow[720 + 144 + pp]
                      + rot[i*3+2] * lrow[720 + 288 + pp] + t0;
                    int h = pp / 12, pl = pp - h * 12;
                    if (pl < 4) {
                        kp_out[(size_t)n * 144 + (h * 4 + pl) * 3 + i] = f2bf(v);
                        kprot[r * 144 + (h * 4 + pl) * 3 + i] = v;
                    } else {
                        vp_out[(size_t)n * 288 + (h * 8 + (pl - 4)) * 3 + i] = f2bf(v);
                    }
                }
            }
        }
    }
    __syncthreads();
    if (t < 96) {
        int r = t / 12, h = t - r * 12;
        float ss = 0.f;
        #pragma unroll
        for (int d = 0; d < 12; ++d) {
            float v = kprot[r * 144 + h * 12 + d];
            ss += v * v;
        }
        k2_out[(size_t)(n0 + r) * 12 + h] = ss;
    }
}

// ------------------------------- K5: fused attention (j-split S=2) ---------
// partial layout per (i,s), 2048 floats:
//   [0:1536)    o_pair unnorm [h*128+c]
//   [1536:1728) o unnorm (192)
//   [1728:2016) o_pt unnorm (288)
//   [2016:2028) m (12)   [2028:2040) l (12)
__global__ __launch_bounds__(256, 4) void k_attn(
    const float* __restrict__ z, const float* __restrict__ mask,
    const float* __restrict__ head_w, const float* __restrict__ wb,
    const float* __restrict__ bb,
    const float* __restrict__ q_ws, const float* __restrict__ qp_ws,
    const float* __restrict__ k2_ws,
    const unsigned short* __restrict__ k_bf, const unsigned short* __restrict__ v_bf,
    const unsigned short* __restrict__ kp_bf, const unsigned short* __restrict__ vp_bf,
    float* __restrict__ pbuf)
{
    const int i  = blockIdx.x;
    const int sj = blockIdx.y;                 // 0 / 1
    const int jbase = sj * 384;
    const int t = threadIdx.x;
    const int lane = t & 63, wv = t >> 6;
    const int quad = lane >> 4, lcol = lane & 15;

    __shared__ short zb[64 * 136];             // swizzled bf16 z tile
    __shared__ float L[64 * 17];               // logits [jl][h]; reused as vbuf
    __shared__ float Pt[16 * 68];              // softmax weights [h][jl]
    __shared__ float qs[192], qps[144], ulrc[384];
    __shared__ float m_s[16], l_s[16], alph_s[16];
    __shared__ float cpt_s[16], q2s[16], cbb_s[16];

    const float c_qk = 0.14433756729740643f;   // 1/sqrt(3*CH)
    const float c_b  = 0.57735026918962576f;   // 1/sqrt(3)

    if (t < 192) qs[t]  = q_ws[(size_t)i * 192 + t];
    if (t < 144) qps[t] = qp_ws[(size_t)i * 144 + t];
    if (t >= 192 && t < 208) { int u = t - 192; m_s[u] = -1e30f; l_s[u] = 0.f; alph_s[u] = 1.f; }
    for (int x = t; x < 384; x += 256) ulrc[x] = mask[(size_t)(jbase + x) * 5];
    for (int x = t; x < 4 * 68; x += 256) Pt[12 * 68 + x] = 0.f;   // pad heads
    const float ulr_i = mask[(size_t)i * 5];

    // wb B-fragments, resident in registers
    s16x8 wbf[4];
    #pragma unroll
    for (int kb = 0; kb < 4; ++kb) {
        #pragma unroll
        for (int j = 0; j < 8; ++j) {
            int c = kb * 32 + quad * 8 + j;
            wbf[kb][j] = (lcol < 12) ? (short)f2bf(wb[(size_t)lcol * 128 + c]) : (short)0;
        }
    }
    __syncthreads();
    if (t < 16) {
        if (t < 12) {
            float ss = 0.f;
            #pragma unroll
            for (int d = 0; d < 12; ++d) { float v = qps[t * 12 + d]; ss += v * v; }
            q2s[t] = ss;
            float x = head_w[t];
            cpt_s[t] = -0.5f * logf(1.f + __expf(x)) * 0.13608276348795434f; // /sqrt(54)
            cbb_s[t] = c_b * bb[t];
        } else { q2s[t] = 0.f; cpt_s[t] = 0.f; cbb_s[t] = 0.f; }
    }

    f32x4 acc_op[2] = { {0.f,0.f,0.f,0.f}, {0.f,0.f,0.f,0.f} };  // o_pair (MFMA C)
    f32x4 acc_s = {0.f,0.f,0.f,0.f};                              // o / o_pt partial

    // value-phase roles: 240 threads x 32 j (two halves)
    int vu = -1, vhalf = 0;
    if (t < 120) { vu = t; vhalf = 0; }
    else if (t >= 128 && t < 248) { vu = t - 128; vhalf = 1; }
    int vrole = -1; const unsigned int* vsrc = nullptr; int vstride = 0, voff = 0;
    if (vu >= 0) {
        if (vu < 48) { vrole = vu >> 2;      vsrc = (const unsigned int*)v_bf;  vstride = 96;  voff = vu * 2; }
        else         { vrole = (vu - 48) / 6; vsrc = (const unsigned int*)vp_bf; vstride = 144; voff = (vu - 48) * 2; }
    }

    for (int tt = 0; tt < 6; ++tt) {
        const int j0 = jbase + tt * 64;
        __syncthreads();   // A: protect zb/Pt/L from previous tile readers

        // ---- stage z tile (swizzled 16B chunks) ----
        {
            const float* zrow = z + (size_t)i * 98304 + (size_t)j0 * 128;
            #pragma unroll
            for (int sx = 0; sx < 8; ++sx) {
                int idx = t + sx * 256;
                f32x4 v = *(const f32x4*)(zrow + idx * 4);
                int jl = idx >> 5, cq = idx & 31;
                int ch = (cq >> 1) ^ ((jl >> 3) & 3);
                uint2 pk;
                pk.x = packbf2(v[0], v[1]);
                pk.y = packbf2(v[2], v[3]);
                *(uint2*)&zb[jl * 136 + ch * 8 + (cq & 1) * 4] = pk;
            }
        }
        __syncthreads();   // B

        // ---- bias via MFMA: L[jl][h] = c_b*(z@wb^T) + c_b*bb ----
        {
            f32x4 d = {0.f,0.f,0.f,0.f};
            const int sigm = ((wv * 16 + lcol) >> 3) & 3;
            #pragma unroll
            for (int kb = 0; kb < 4; ++kb) {
                s16x8 a = *(const s16x8*)&zb[(wv * 16 + lcol) * 136 + ((kb * 4 + quad) ^ sigm) * 8];
                d = __builtin_amdgcn_mfma_f32_16x16x32_bf16(a, wbf[kb], d, 0, 0, 0);
            }
            if (lcol < 12) {
                #pragma unroll
                for (int r = 0; r < 4; ++r)
                    L[(wv * 16 + quad * 4 + r) * 17 + lcol] = c_b * d[r] + cbb_s[lcol];
            }
        }
        __syncthreads();   // C

        // ---- qk + point-dist + mask: item e=(jl,h), 12 lanes per k-row ----
        #pragma unroll
        for (int es = 0; es < 3; ++es) {
            int e = t + es * 256;
            int jl = e / 12, h = e - jl * 12;
            int jr = j0 + jl;
            const unsigned short* kr = k_bf + (size_t)jr * 192 + h * 16;
            uint4 k0 = *(const uint4*)kr;
            uint4 k1 = *(const uint4*)(kr + 8);
            const unsigned short* pr = kp_bf + (size_t)jr * 144 + h * 12;
            uint2 p0 = *(const uint2*)pr;
            uint2 p1 = *(const uint2*)(pr + 4);
            uint2 p2 = *(const uint2*)(pr + 8);
            float K2 = k2_ws[(size_t)jr * 12 + h];
            f32x4 qa = *(const f32x4*)&qs[h * 16];
            f32x4 qb = *(const f32x4*)&qs[h * 16 + 4];
            f32x4 qc = *(const f32x4*)&qs[h * 16 + 8];
            f32x4 qd = *(const f32x4*)&qs[h * 16 + 12];
            f32x4 pa = *(const f32x4*)&qps[h * 12];
            f32x4 pb = *(const f32x4*)&qps[h * 12 + 4];
            f32x4 pc = *(const f32x4*)&qps[h * 12 + 8];
            const unsigned* ka = (const unsigned*)&k0;
            const unsigned* kb2 = (const unsigned*)&k1;
            float qk = 0.f;
            qk += qa[0]*bf2f((unsigned short)(ka[0]&0xffffu)) + qa[1]*bf2f((unsigned short)(ka[0]>>16));
            qk += qa[2]*bf2f((unsigned short)(ka[1]&0xffffu)) + qa[3]*bf2f((unsigned short)(ka[1]>>16));
            qk += qb[0]*bf2f((unsigned short)(ka[2]&0xffffu)) + qb[1]*bf2f((unsigned short)(ka[2]>>16));
            qk += qb[2]*bf2f((unsigned short)(ka[3]&0xffffu)) + qb[3]*bf2f((unsigned short)(ka[3]>>16));
            qk += qc[0]*bf2f((unsigned short)(kb2[0]&0xffffu)) + qc[1]*bf2f((unsigned short)(kb2[0]>>16));
            qk += qc[2]*bf2f((unsigned short)(kb2[1]&0xffffu)) + qc[3]*bf2f((unsigned short)(kb2[1]>>16));
            qk += qd[0]*bf2f((unsigned short)(kb2[2]&0xffffu)) + qd[1]*bf2f((unsigned short)(kb2[2]>>16));
            qk += qd[2]*bf2f((unsigned short)(kb2[3]&0xffffu)) + qd[3]*bf2f((unsigned short)(kb2[3]>>16));
            float dp = 0.f;
            dp += pa[0]*bf2f((unsigned short)(p0.x&0xffffu)) + pa[1]*bf2f((unsigned short)(p0.x>>16));
            dp += pa[2]*bf2f((unsigned short)(p0.y&0xffffu)) + pa[3]*bf2f((unsigned short)(p0.y>>16));
            dp += pb[0]*bf2f((unsigned short)(p1.x&0xffffu)) + pb[1]*bf2f((unsigned short)(p1.x>>16));
            dp += pb[2]*bf2f((unsigned short)(p1.y&0xffffu)) + pb[3]*bf2f((unsigned short)(p1.y>>16));
            dp += pc[0]*bf2f((unsigned short)(p2.x&0xffffu)) + pc[1]*bf2f((unsigned short)(p2.x>>16));
            dp += pc[2]*bf2f((unsigned short)(p2.y&0xffffu)) + pc[3]*bf2f((unsigned short)(p2.y>>16));
            float ptt = cpt_s[h] * (q2s[h] + K2 - 2.f * dp);
            float lg = c_qk * qk + ptt + 1e5f * (ulr_i * ulrc[tt * 64 + jl] - 1.f);
            L[jl * 17 + h] += lg;
        }
        __syncthreads();   // D

        // ---- online softmax update (16 lanes per head) ----
        if (t < 192) {
            int h = t >> 4, u = t & 15;
            float v0 = L[(u * 4 + 0) * 17 + h];
            float v1 = L[(u * 4 + 1) * 17 + h];
            float v2 = L[(u * 4 + 2) * 17 + h];
            float v3 = L[(u * 4 + 3) * 17 + h];
            float mx = fmaxf(fmaxf(v0, v1), fmaxf(v2, v3));
            for (int mk = 1; mk < 16; mk <<= 1) mx = fmaxf(mx, __shfl_xor(mx, mk, 16));
            float mold = m_s[h];
            float mnew = fmaxf(mold, mx);
            float w0 = __expf(v0 - mnew), w1 = __expf(v1 - mnew);
            float w2 = __expf(v2 - mnew), w3 = __expf(v3 - mnew);
            Pt[h * 68 + u * 4 + 0] = w0;
            Pt[h * 68 + u * 4 + 1] = w1;
            Pt[h * 68 + u * 4 + 2] = w2;
            Pt[h * 68 + u * 4 + 3] = w3;
            float sm = w0 + w1 + w2 + w3;
            for (int mk = 1; mk < 16; mk <<= 1) sm += __shfl_xor(sm, mk, 16);
            if (u == 0) {
                float al = __expf(mold - mnew);
                m_s[h] = mnew; alph_s[h] = al;
                l_s[h] = l_s[h] * al + sm;
            }
        }
        __syncthreads();   // E

        // ---- o_pair MFMA: D[h][c] += P(16x64) @ z(64x128) ----
        {
            float al[4];
            #pragma unroll
            for (int r = 0; r < 4; ++r) al[r] = alph_s[quad * 4 + r];
            #pragma unroll
            for (int nt = 0; nt < 2; ++nt)
                #pragma unroll
                for (int r = 0; r < 4; ++r) acc_op[nt][r] *= al[r];
            #pragma unroll
            for (int kb = 0; kb < 2; ++kb) {
                f32x4 pa = *(const f32x4*)&Pt[lcol * 68 + kb * 32 + quad * 8];
                f32x4 pb = *(const f32x4*)&Pt[lcol * 68 + kb * 32 + quad * 8 + 4];
                union { s16x8 v; unsigned u[4]; } af;
                af.u[0] = packbf2(pa[0], pa[1]);
                af.u[1] = packbf2(pa[2], pa[3]);
                af.u[2] = packbf2(pb[0], pb[1]);
                af.u[3] = packbf2(pb[2], pb[3]);
                #pragma unroll
                for (int nt = 0; nt < 2; ++nt) {
                    int c = wv * 32 + nt * 16 + lcol;
                    int csw = ((c >> 3) ^ quad) * 8 + (c & 7);
                    s16x8 bfg;
                    #pragma unroll
                    for (int j = 0; j < 8; ++j)
                        bfg[j] = zb[(kb * 32 + quad * 8 + j) * 136 + csw];
                    acc_op[nt] = __builtin_amdgcn_mfma_f32_16x16x32_bf16(af.v, bfg, acc_op[nt], 0, 0, 0);
                }
            }
        }
        // ---- scalar o / o_pt ----
        if (vu >= 0) {
            float alpha = alph_s[vrole];
            f32x4 a = acc_s;
            a[0] *= alpha; a[1] *= alpha; a[2] *= alpha; a[3] *= alpha;
            const float* prow = &Pt[vrole * 68 + vhalf * 32];
            const unsigned int* src = vsrc + (size_t)(j0 + vhalf * 32) * vstride + voff;
            #pragma unroll 4
            for (int jj = 0; jj < 32; jj += 4) {
                f32x4 p = *(const f32x4*)(prow + jj);
                #pragma unroll
                for (int m = 0; m < 4; ++m) {
                    uint2 w = *(const uint2*)(src + (size_t)(jj + m) * vstride);
                    float pm = p[m];
                    a[0] += pm * bf2f((unsigned short)(w.x & 0xffffu));
                    a[1] += pm * bf2f((unsigned short)(w.x >> 16));
                    a[2] += pm * bf2f((unsigned short)(w.y & 0xffffu));
                    a[3] += pm * bf2f((unsigned short)(w.y >> 16));
                }
            }
            acc_s = a;
        }
    }

    // ------------------------ partial epilogue -----------------------------
    float* pb = pbuf + ((size_t)i * 2 + sj) * 2048;
    // o_pair unnormalized
    #pragma unroll
    for (int nt = 0; nt < 2; ++nt)
        #pragma unroll
        for (int r = 0; r < 4; ++r) {
            int h = quad * 4 + r;
            if (h < 12)
                pb[h * 128 + wv * 32 + nt * 16 + lcol] = acc_op[nt][r];
        }
    if (t < 12) { pb[2016 + t] = m_s[t]; pb[2028 + t] = l_s[t]; }
    // combine value halves via L (safe: no L readers after last softmax)
    float* vbuf = L;
    if (vu >= 0) {
        #pragma unroll
        for (int m = 0; m < 4; ++m) vbuf[(vu * 2 + vhalf) * 4 + m] = acc_s[m];
    }
    __syncthreads();
    if (t < 120) {
        float f[4];
        #pragma unroll
        for (int m = 0; m < 4; ++m)
            f[m] = vbuf[(t * 2) * 4 + m] + vbuf[(t * 2 + 1) * 4 + m];
        f32x4 o = { f[0], f[1], f[2], f[3] };
        if (t < 48) *(f32x4*)(pb + 1536 + t * 4) = o;
        else        *(f32x4*)(pb + 1728 + (t - 48) * 4) = o;
    }
}

// ------------------------------- K6: merge partials + epilogue -------------
__global__ __launch_bounds__(256) void k_attn_fin(
    const float* __restrict__ pbuf,
    const float* __restrict__ r_rot, const float* __restrict__ r_trans,
    float* __restrict__ cat)
{
    const int i = blockIdx.x;
    const int t = threadIdx.x;
    __shared__ float sw0[12], sw1[12], optb[288];
    const float* pb0 = pbuf + (size_t)i * 2 * 2048;
    const float* pb1 = pb0 + 2048;

    if (t < 12) {
        float m0 = pb0[2016 + t], m1 = pb1[2016 + t];
        float M = fmaxf(m0, m1);
        float w0 = __expf(m0 - M), w1 = __expf(m1 - M);
        float l = w0 * pb0[2028 + t] + w1 * pb1[2028 + t];
        float inv = 1.f / l;
        sw0[t] = w0 * inv; sw1[t] = w1 * inv;
    }
    __syncthreads();
    float* crow = cat + (size_t)i * 2112;
    if (t < 192) {
        int h = t >> 4;
        crow[t] = sw0[h] * pb0[1536 + t] + sw1[h] * pb1[1536 + t];
    }
    for (int x = t; x < 288; x += 256) {
        int h = x / 24;
        optb[x] = sw0[h] * pb0[1728 + x] + sw1[h] * pb1[1728 + x];
    }
    for (int x = t; x < 1536; x += 256) {
        int h = x >> 7;
        crow[576 + x] = sw0[h] * pb0[x] + sw1[h] * pb1[x];
    }
    __syncthreads();
    if (t < 96) {   // invert frame 0, write o_pt xyz + norm
        int hp = t;
        const float* rot = r_rot + (size_t)i * 45;
        float d0 = optb[hp * 3 + 0] - r_trans[(size_t)i * 15 + 0];
        float d1 = optb[hp * 3 + 1] - r_trans[(size_t)i * 15 + 1];
        float d2 = optb[hp * 3 + 2] - r_trans[(size_t)i * 15 + 2];
        float f0 = rot[0] * d0 + rot[3] * d1 + rot[6] * d2;
        float f1 = rot[1] * d0 + rot[4] * d1 + rot[7] * d2;
        float f2 = rot[2] * d0 + rot[5] * d1 + rot[8] * d2;
        crow[192 + hp] = f0;
        crow[288 + hp] = f1;
        crow[384 + hp] = f2;
        crow[480 + hp] = sqrtf(f0 * f0 + f1 * f1 + f2 * f2 + 1e-8f);
    }
}

// ------------------------------- K7: out += cat @ wout.T (split-K atomic) --
__global__ __launch_bounds__(256) void k_gemm(
    const float* __restrict__ cat, const float* __restrict__ wout,
    float* __restrict__ out)
{
    const int mb = blockIdx.x, nb = blockIdx.y, sb = blockIdx.z;
    const int t = threadIdx.x;
    __shared__ float At[16 * 132];
    __shared__ float Bt[16 * 68];
    const int m0 = mb * 128, n0 = nb * 64, koff = sb * 176;
    const int tx = t & 15, ty = t >> 4;
    float acc[8][4] = {};

    for (int ch = 0; ch < 11; ++ch) {
        const int kb = koff + ch * 16;
        __syncthreads();
        #pragma unroll
        for (int sx = 0; sx < 2; ++sx) {
            int idx = t + sx * 256;
            int row = idx >> 2, k4 = idx & 3;
            f32x4 v = *(const f32x4*)(cat + (size_t)(m0 + row) * 2112 + kb + k4 * 4);
            At[(k4 * 4 + 0) * 132 + row] = v[0];
            At[(k4 * 4 + 1) * 132 + row] = v[1];
            At[(k4 * 4 + 2) * 132 + row] = v[2];
            At[(k4 * 4 + 3) * 132 + row] = v[3];
        }
        {
            int c = t >> 2, k4 = t & 3;
            f32x4 v = *(const f32x4*)(wout + (size_t)(n0 + c) * 2112 + kb + k4 * 4);
            Bt[(k4 * 4 + 0) * 68 + c] = v[0];
            Bt[(k4 * 4 + 1) * 68 + c] = v[1];
            Bt[(k4 * 4 + 2) * 68 + c] = v[2];
            Bt[(k4 * 4 + 3) * 68 + c] = v[3];
        }
        __syncthreads();
        #pragma unroll
        for (int kk = 0; kk < 16; ++kk) {
            f32x4 b  = *(const f32x4*)&Bt[kk * 68 + tx * 4];
            f32x4 a0 = *(const f32x4*)&At[kk * 132 + ty * 8];
            f32x4 a1 = *(const f32x4*)&At[kk * 132 + ty * 8 + 4];
            #pragma unroll
            for (int r = 0; r < 4; ++r)
                #pragma unroll
                for (int c = 0; c < 4; ++c) acc[r][c] += a0[r] * b[c];
            #pragma unroll
            for (int r = 0; r < 4; ++r)
                #pragma unroll
                for (int c = 0; c < 4; ++c) acc[r + 4][c] += a1[r] * b[c];
        }
    }
    #pragma unroll
    for (int r = 0; r < 8; ++r) {
        float* orow = out + (size_t)(m0 + ty * 8 + r) * 384 + n0 + tx * 4;
        #pragma unroll
        for (int c = 0; c < 4; ++c) atomicAdd(orow + c, acc[r][c]);
    }
}

// ------------------------------- launch ------------------------------------
extern "C" void kernel_launch(void* const* d_in, const int* in_sizes, int n_in,
                              void* d_out, int out_size, void* d_ws, size_t ws_size,
                              hipStream_t stream)
{
    const float* s       = (const float*)d_in[0];
    const float* z       = (const float*)d_in[1];
    const float* r_rot   = (const float*)d_in[2];
    const float* r_trans = (const float*)d_in[3];
    const float* mask    = (const float*)d_in[4];
    const float* wq      = (const float*)d_in[5];
    const float* bq      = (const float*)d_in[6];
    const float* wkv     = (const float*)d_in[7];
    const float* bkv     = (const float*)d_in[8];
    const float* wqp     = (const float*)d_in[9];
    const float* bqp     = (const float*)d_in[10];
    const float* wkvp    = (const float*)d_in[11];
    const float* bkvp    = (const float*)d_in[12];
    const float* wb      = (const float*)d_in[13];
    const float* bb      = (const float*)d_in[14];
    const float* head_w  = (const float*)d_in[15];
    const float* wout    = (const float*)d_in[16];
    const float* bout    = (const float*)d_in[17];
    const float* wexp    = (const float*)d_in[18];
    const float* bexp    = (const float*)d_in[19];
    const float* ln_g    = (const float*)d_in[20];
    const float* ln_b    = (const float*)d_in[21];
    // d_in[22]=ww, d_in[23]=bw unused: softmax over size-1 axis == 1.0

    float* wsf  = (float*)d_ws;
    float* se0  = wsf;                 // 294912
    float* qf   = wsf + 294912;        // 147456
    float* qpf  = wsf + 442368;        // 110592
    float* k2w  = wsf + 552960;        // 9216
    float* catb = wsf + 562176;        // 1622016 (aliases se_raw, lin)
    float* pbuf = wsf + 2184192;       // 3145728 (768*2*2048)
    float* se_raw = catb;
    float* lin    = catb;
    unsigned short* kbf  = (unsigned short*)((char*)d_ws + 22892544);
    unsigned short* vbf  = kbf + 147456;
    unsigned short* kpbf = vbf + 147456;
    unsigned short* vpbf = kpbf + 110592;
    float* out = (float*)d_out;

    k_init<<<1152, 256, 0, stream>>>(bout, out);
    k_se_gemm<<<dim3(24, 12), 256, 0, stream>>>(s, wexp, bexp, se_raw);
    k_ln<<<192, 256, 0, stream>>>(se_raw, ln_g, ln_b, se0);
    k_proj_gemm<<<dim3(24, 36), 256, 0, stream>>>(se0, wq, bq, wkv, bkv,
                                                  wqp, bqp, wkvp, bkvp, lin);
    k_post<<<96, 256, 0, stream>>>(lin, r_rot, r_trans,
                                   qf, kbf, vbf, qpf, kpbf, vpbf, k2w);
    k_attn<<<dim3(768, 2), 256, 0, stream>>>(z, mask, head_w, wb, bb,
                                             qf, qpf, k2w, kbf, vbf, kpbf, vpbf,
                                             pbuf);
    k_attn_fin<<<768, 256, 0, stream>>>(pbuf, r_rot, r_trans, catb);
    k_gemm<<<dim3(6, 6, 12), 256, 0, stream>>>(catb, wout, out);
}

// Round 4
// 554.587 us; speedup vs baseline: 1.3949x; 1.3949x over previous
//
#include <hip/hip_runtime.h>
#include <hip/hip_bf16.h>
#include <stdint.h>

// ---------------------------------------------------------------------------
// InvariantPointAttention, B=1 N=768 CS=384 CZ=128 CH=16 H=12 PQ=4 PV=8
// weight = softmax over size-1 axis == 1.0  =>  _mix(x) == x[:,:,0] (frame 0).
//
// K0 k_prep   : cast s/wexp0/[wq|wkv|wqp|wkvp]/wout to bf16, build bcat
// K1 k_mm     : generic bf16 MFMA GEMM (64x64 tile, fp32 accum, opt bias,
//               opt split-K via blockIdx.z) -- used for se / proj / out
// K2 k_ln     : se0_bf = bf16(LN(se_raw) * g + b)
// K3 k_post   : split q/k/v, rotate points, bf16 casts, K2 = sum k_pts^2
// K4 k_attn   : flash attention, one block per query row, pipelined z
//               prefetch (regs->LDS), 4 barriers/tile, cat written bf16
// K5 k_out_red: out = bout + sum of 6 split-K parts
// ---------------------------------------------------------------------------

typedef float  f32x4 __attribute__((ext_vector_type(4)));
typedef short  s16x8 __attribute__((ext_vector_type(8)));

__device__ __forceinline__ float bf2f(unsigned short u) {
    union { unsigned int i; float f; } v; v.i = ((unsigned int)u) << 16; return v.f;
}
__device__ __forceinline__ unsigned short f2bf(float f) {
    union { float f; unsigned int i; } v; v.f = f;
    unsigned int r = v.i + 0x7fffu + ((v.i >> 16) & 1u);
    return (unsigned short)(r >> 16);
}
__device__ __forceinline__ unsigned packbf2(float a, float b) {
    return (unsigned)f2bf(a) | ((unsigned)f2bf(b) << 16);
}
__device__ __forceinline__ float bval(int c,
    const float* bq, const float* bkv, const float* bqp, const float* bkvp)
{
    if (c < 192)      return bq[c];
    else if (c < 576) return bkv[c - 192];
    else if (c < 720) return bqp[c - 576];
    else              return bkvp[c - 720];
}

// ------------------------------- K0: prep casts ----------------------------
__global__ __launch_bounds__(256) void k_prep(
    const float* __restrict__ s, const float* __restrict__ wexp,
    const float* __restrict__ wq, const float* __restrict__ wkv,
    const float* __restrict__ wqp, const float* __restrict__ wkvp,
    const float* __restrict__ wout,
    const float* __restrict__ bq, const float* __restrict__ bkv,
    const float* __restrict__ bqp, const float* __restrict__ bkvp,
    unsigned short* __restrict__ s_bf, unsigned short* __restrict__ we_bf,
    unsigned short* __restrict__ wc_bf, unsigned short* __restrict__ wo_bf,
    float* __restrict__ bcat)
{
    const int x = blockIdx.x * 256 + threadIdx.x;
    if (x >= 1696896) return;
    if (x < 294912)            s_bf[x] = f2bf(s[x]);
    else if (x < 442368)       we_bf[x - 294912] = f2bf(wexp[x - 294912]);
    else if (x < 516096)       wc_bf[x - 442368] = f2bf(wq[x - 442368]);
    else if (x < 663552)       wc_bf[73728 + (x - 516096)] = f2bf(wkv[x - 516096]);
    else if (x < 718848)       wc_bf[221184 + (x - 663552)] = f2bf(wqp[x - 663552]);
    else if (x < 884736)       wc_bf[276480 + (x - 718848)] = f2bf(wkvp[x - 718848]);
    else if (x < 1695744)      wo_bf[x - 884736] = f2bf(wout[x - 884736]);
    else {
        int j = x - 1695744;   // < 1152
        bcat[j] = bval(j, bq, bkv, bqp, bkvp);
    }
}

// ------------------------------- K1: generic bf16 MFMA GEMM ----------------
// C[m][n] = sum_k A[m][k] * B[n][k]  (+ bias[n]); 64x64 tile, K-chunk 32.
__global__ __launch_bounds__(256) void k_mm(
    const unsigned short* __restrict__ A, int lda,
    const unsigned short* __restrict__ B, int ldb,
    float* __restrict__ C, int ldc, const float* __restrict__ bias,
    int nk, size_t pstride)
{
    const int m0 = blockIdx.x * 64, n0 = blockIdx.y * 64;
    const int koff = blockIdx.z * nk * 32;
    C += (size_t)blockIdx.z * pstride;
    const int t = threadIdx.x;
    const int lane = t & 63, wave = t >> 6, quad = lane >> 4, lcol = lane & 15;
    const int mh = (wave & 1) * 32, nh = (wave >> 1) * 32;
    __shared__ unsigned short As[64 * 40];
    __shared__ unsigned short Bs[64 * 40];
    const int lr = t >> 2, ls = (t & 3) * 8;
    const unsigned short* Ap = A + (size_t)(m0 + lr) * lda + koff + ls;
    const unsigned short* Bp = B + (size_t)(n0 + lr) * ldb + koff + ls;
    f32x4 acc[2][2] = {};

    uint4 av = *(const uint4*)Ap;
    uint4 bv = *(const uint4*)Bp;
    for (int kc = 0; kc < nk; ++kc) {
        __syncthreads();
        *(uint4*)&As[lr * 40 + ls] = av;
        *(uint4*)&Bs[lr * 40 + ls] = bv;
        __syncthreads();
        if (kc + 1 < nk) {
            av = *(const uint4*)(Ap + (size_t)(kc + 1) * 32);
            bv = *(const uint4*)(Bp + (size_t)(kc + 1) * 32);
        }
        s16x8 af0 = *(const s16x8*)&As[(mh + lcol) * 40 + quad * 8];
        s16x8 af1 = *(const s16x8*)&As[(mh + 16 + lcol) * 40 + quad * 8];
        s16x8 bf0 = *(const s16x8*)&Bs[(nh + lcol) * 40 + quad * 8];
        s16x8 bf1 = *(const s16x8*)&Bs[(nh + 16 + lcol) * 40 + quad * 8];
        acc[0][0] = __builtin_amdgcn_mfma_f32_16x16x32_bf16(af0, bf0, acc[0][0], 0, 0, 0);
        acc[0][1] = __builtin_amdgcn_mfma_f32_16x16x32_bf16(af0, bf1, acc[0][1], 0, 0, 0);
        acc[1][0] = __builtin_amdgcn_mfma_f32_16x16x32_bf16(af1, bf0, acc[1][0], 0, 0, 0);
        acc[1][1] = __builtin_amdgcn_mfma_f32_16x16x32_bf16(af1, bf1, acc[1][1], 0, 0, 0);
    }
    #pragma unroll
    for (int r = 0; r < 2; ++r)
        #pragma unroll
        for (int c = 0; c < 2; ++c) {
            int gn = n0 + nh + c * 16 + lcol;
            float bv2 = bias ? bias[gn] : 0.f;
            #pragma unroll
            for (int ii = 0; ii < 4; ++ii) {
                int gm = m0 + mh + r * 16 + quad * 4 + ii;
                C[(size_t)gm * ldc + gn] = acc[r][c][ii] + bv2;
            }
        }
}

// ------------------------------- K2: LayerNorm -> bf16 ---------------------
__global__ __launch_bounds__(256) void k_ln(
    const float* __restrict__ se_raw, const float* __restrict__ ln_g,
    const float* __restrict__ ln_b, unsigned short* __restrict__ se0_bf)
{
    const int n = blockIdx.x * 4 + (threadIdx.x >> 6);
    const int lane = threadIdx.x & 63;
    const float* row = se_raw + (size_t)n * 384;
    float v[6], s1 = 0.f, s2 = 0.f;
    #pragma unroll
    for (int q = 0; q < 6; ++q) {
        v[q] = row[lane + q * 64];
        s1 += v[q]; s2 += v[q] * v[q];
    }
    for (int mk = 1; mk < 64; mk <<= 1) {
        s1 += __shfl_xor(s1, mk, 64);
        s2 += __shfl_xor(s2, mk, 64);
    }
    float mu = s1 * (1.f / 384.f);
    float var = s2 * (1.f / 384.f) - mu * mu;
    float rs = rsqrtf(fmaxf(var, 0.f) + 1e-5f);
    unsigned short* orow = se0_bf + (size_t)n * 384;
    #pragma unroll
    for (int q = 0; q < 6; ++q) {
        int c = lane + q * 64;
        orow[c] = f2bf((v[q] - mu) * rs * ln_g[c] + ln_b[c]);
    }
}

// ------------------------------- K3: post-process --------------------------
__global__ __launch_bounds__(256) void k_post(
    const float* __restrict__ lin,
    const float* __restrict__ r_rot, const float* __restrict__ r_trans,
    float* __restrict__ q_out, unsigned short* __restrict__ k_out,
    unsigned short* __restrict__ v_out, float* __restrict__ qp_out,
    unsigned short* __restrict__ kp_out, unsigned short* __restrict__ vp_out,
    float* __restrict__ k2_out)
{
    const int n0 = blockIdx.x * 8;
    const int t = threadIdx.x;
    __shared__ float kprot[8 * 144];

    for (int r = 0; r < 8; ++r) {
        const int n = n0 + r;
        const float* lrow = lin + (size_t)n * 1152;
        const float* rot = r_rot + (size_t)n * 45;        // frame 0
        for (int u = t; u < 1152; u += 256) {
            if (u < 192) {
                q_out[(size_t)n * 192 + u] = lrow[u];
            } else if (u < 576) {
                int l2 = u - 192, h = l2 >> 5, c = l2 & 31;
                float v = lrow[u];
                if (c < 16) k_out[(size_t)n * 192 + h * 16 + c] = f2bf(v);
                else        v_out[(size_t)n * 192 + h * 16 + (c - 16)] = f2bf(v);
            } else {
                int y = u - 576;
                int pt = y / 3, i = y - pt * 3;
                float t0 = r_trans[(size_t)n * 15 + i];
                float v;
                if (pt < 48) {
                    v = rot[i*3+0] * lrow[576 + pt]
                      + rot[i*3+1] * lrow[576 + 48 + pt]
                      + rot[i*3+2] * lrow[576 + 96 + pt] + t0;
                    qp_out[(size_t)n * 144 + pt * 3 + i] = v;
                } else {
                    int pp = pt - 48;
                    v = rot[i*3+0] * lrow[720 + pp]
                      + rot[i*3+1] * lrow[720 + 144 + pp]
                      + rot[i*3+2] * lrow[720 + 288 + pp] + t0;
                    int h = pp / 12, pl = pp - h * 12;
                    if (pl < 4) {
                        kp_out[(size_t)n * 144 + (h * 4 + pl) * 3 + i] = f2bf(v);
                        kprot[r * 144 + (h * 4 + pl) * 3 + i] = v;
                    } else {
                        vp_out[(size_t)n * 288 + (h * 8 + (pl - 4)) * 3 + i] = f2bf(v);
                    }
                }
            }
        }
    }
    __syncthreads();
    if (t < 96) {
        int r = t / 12, h = t - r * 12;
        float ss = 0.f;
        #pragma unroll
        for (int d = 0; d < 12; ++d) {
            float v = kprot[r * 144 + h * 12 + d];
            ss += v * v;
        }
        k2_out[(size_t)(n0 + r) * 12 + h] = ss;
    }
}

// ------------------------------- K4: fused attention -----------------------
__global__ __launch_bounds__(256) void k_attn(
    const float* __restrict__ z, const float* __restrict__ mask,
    const float* __restrict__ head_w, const float* __restrict__ wb,
    const float* __restrict__ bb,
    const float* __restrict__ r_rot, const float* __restrict__ r_trans,
    const float* __restrict__ q_ws, const float* __restrict__ qp_ws,
    const float* __restrict__ k2_ws,
    const unsigned short* __restrict__ k_bf, const unsigned short* __restrict__ v_bf,
    const unsigned short* __restrict__ kp_bf, const unsigned short* __restrict__ vp_bf,
    unsigned short* __restrict__ cat)
{
    const int i = blockIdx.x;
    const int t = threadIdx.x;
    const int lane = t & 63, wv = t >> 6;
    const int quad = lane >> 4, lcol = lane & 15;

    __shared__ short zb[64 * 136];             // swizzled bf16 z tile (17.4 KB)
    __shared__ float L[64 * 17];               // logits [jl][h]; reused as vbuf
    __shared__ float Pt[16 * 68];              // softmax weights [h][jl]
    __shared__ float qs[192], qps[144];
    __shared__ float ulra[768];
    __shared__ float m_s[16], l_s[16], alph_s[16], linv_s[16];
    __shared__ float optb[288];

    const float c_qk = 0.14433756729740643f;   // 1/sqrt(3*CH)
    const float c_b  = 0.57735026918962576f;   // 1/sqrt(3)

    if (t < 192) qs[t]  = q_ws[(size_t)i * 192 + t];
    if (t < 144) qps[t] = qp_ws[(size_t)i * 144 + t];
    if (t >= 192 && t < 208) { int u = t - 192; m_s[u] = -1e30f; l_s[u] = 0.f; alph_s[u] = 1.f; }
    for (int x = t; x < 768; x += 256) ulra[x] = mask[(size_t)x * 5];
    for (int x = t; x < 4 * 68; x += 256) Pt[12 * 68 + x] = 0.f;   // pad heads
    const float ulr_i = mask[(size_t)i * 5];

    // wb B-fragments, resident in registers
    s16x8 wbf[4];
    #pragma unroll
    for (int kb = 0; kb < 4; ++kb) {
        #pragma unroll
        for (int j = 0; j < 8; ++j) {
            int c = kb * 32 + quad * 8 + j;
            wbf[kb][j] = (lcol < 12) ? (short)f2bf(wb[(size_t)lcol * 128 + c]) : (short)0;
        }
    }
    __syncthreads();

    // per-thread hoisted q/qp/consts for the logit phase (head = lcol, clamped)
    const int hh = (lcol < 12) ? lcol : 11;
    f32x4 qv[4], qpv[3];
    float q2_r = 0.f;
    #pragma unroll
    for (int m = 0; m < 4; ++m) qv[m] = *(const f32x4*)&qs[hh * 16 + m * 4];
    #pragma unroll
    for (int m = 0; m < 3; ++m) {
        qpv[m] = *(const f32x4*)&qps[hh * 12 + m * 4];
        #pragma unroll
        for (int e = 0; e < 4; ++e) q2_r += qpv[m][e] * qpv[m][e];
    }
    float xh = head_w[hh];
    const float cpt_r = -0.5f * logf(1.f + __expf(xh)) * 0.13608276348795434f;
    const float cbb_r = c_b * bb[hh];

    f32x4 acc_op[2] = { {0.f,0.f,0.f,0.f}, {0.f,0.f,0.f,0.f} };  // o_pair (MFMA C)
    f32x4 acc_s = {0.f,0.f,0.f,0.f};                              // o / o_pt partial

    // value-phase roles: 240 threads x 32 j (two halves)
    int vu = -1, vhalf = 0;
    if (t < 120) { vu = t; vhalf = 0; }
    else if (t >= 128 && t < 248) { vu = t - 128; vhalf = 1; }
    int vrole = -1; const unsigned int* vsrc = nullptr; int vstride = 0, voff = 0;
    if (vu >= 0) {
        if (vu < 48) { vrole = vu >> 2;       vsrc = (const unsigned int*)v_bf;  vstride = 96;  voff = vu * 2; }
        else         { vrole = (vu - 48) / 6; vsrc = (const unsigned int*)vp_bf; vstride = 144; voff = (vu - 48) * 2; }
    }

    // prefetch z tile 0 into registers
    const float* zbase = z + (size_t)i * 98304;
    f32x4 zr[8];
    #pragma unroll
    for (int sx = 0; sx < 8; ++sx)
        zr[sx] = *(const f32x4*)(zbase + (size_t)(t + sx * 256) * 4);

    const int jlb = wv * 16 + quad * 4;
    const int zrow = wv * 16 + lcol;
    const int sigm = (zrow >> 3) & 3;

    for (int tt = 0; tt < 12; ++tt) {
        const int j0 = tt * 64;
        __syncthreads();   // A: previous tile's zb/Pt readers done

        // ---- store prefetched z tile (swizzled 16B chunks) ----
        #pragma unroll
        for (int sx = 0; sx < 8; ++sx) {
            int idx = t + sx * 256;
            int jl = idx >> 5, cq = idx & 31;
            int ch = (cq >> 1) ^ ((jl >> 3) & 3);
            uint2 pk;
            pk.x = packbf2(zr[sx][0], zr[sx][1]);
            pk.y = packbf2(zr[sx][2], zr[sx][3]);
            *(uint2*)&zb[jl * 136 + ch * 8 + (cq & 1) * 4] = pk;
        }
        __syncthreads();   // B

        // ---- issue next z tile loads (overlap with whole tile compute) ----
        if (tt < 11) {
            const float* znext = zbase + (size_t)(tt + 1) * 8192;
            #pragma unroll
            for (int sx = 0; sx < 8; ++sx)
                zr[sx] = *(const f32x4*)(znext + (size_t)(t + sx * 256) * 4);
        }
        // ---- issue k/kp/K2 loads for this thread's 4 j-rows ----
        uint4 ka[4], kb4[4]; uint2 p0[4], p1[4], p2[4]; float K2r[4];
        #pragma unroll
        for (int r = 0; r < 4; ++r) {
            int jr = j0 + jlb + r;
            const unsigned short* kr = k_bf + (size_t)jr * 192 + hh * 16;
            ka[r]  = *(const uint4*)kr;
            kb4[r] = *(const uint4*)(kr + 8);
            const unsigned short* pr = kp_bf + (size_t)jr * 144 + hh * 12;
            p0[r] = *(const uint2*)pr;
            p1[r] = *(const uint2*)(pr + 4);
            p2[r] = *(const uint2*)(pr + 8);
            K2r[r] = k2_ws[(size_t)jr * 12 + hh];
        }

        // ---- bias via MFMA (covers the L2 latency of the loads above) ----
        f32x4 d = {0.f, 0.f, 0.f, 0.f};
        #pragma unroll
        for (int kb = 0; kb < 4; ++kb) {
            s16x8 a = *(const s16x8*)&zb[zrow * 136 + ((kb * 4 + quad) ^ sigm) * 8];
            d = __builtin_amdgcn_mfma_f32_16x16x32_bf16(a, wbf[kb], d, 0, 0, 0);
        }

        // ---- logits: thread owns (jl = jlb+r, h = lcol) ----
        if (lcol < 12) {
            #pragma unroll
            for (int r = 0; r < 4; ++r) {
                int jl = jlb + r;
                const unsigned* kwa = (const unsigned*)&ka[r];
                const unsigned* kwb = (const unsigned*)&kb4[r];
                float qk = 0.f;
                #pragma unroll
                for (int m = 0; m < 4; ++m) {
                    qk += qv[m >> 1][(m & 1) * 2 + 0] * bf2f((unsigned short)(kwa[m] & 0xffffu));
                    qk += qv[m >> 1][(m & 1) * 2 + 1] * bf2f((unsigned short)(kwa[m] >> 16));
                }
                #pragma unroll
                for (int m = 0; m < 4; ++m) {
                    qk += qv[2 + (m >> 1)][(m & 1) * 2 + 0] * bf2f((unsigned short)(kwb[m] & 0xffffu));
                    qk += qv[2 + (m >> 1)][(m & 1) * 2 + 1] * bf2f((unsigned short)(kwb[m] >> 16));
                }
                float dp = 0.f;
                dp += qpv[0][0] * bf2f((unsigned short)(p0[r].x & 0xffffu));
                dp += qpv[0][1] * bf2f((unsigned short)(p0[r].x >> 16));
                dp += qpv[0][2] * bf2f((unsigned short)(p0[r].y & 0xffffu));
                dp += qpv[0][3] * bf2f((unsigned short)(p0[r].y >> 16));
                dp += qpv[1][0] * bf2f((unsigned short)(p1[r].x & 0xffffu));
                dp += qpv[1][1] * bf2f((unsigned short)(p1[r].x >> 16));
                dp += qpv[1][2] * bf2f((unsigned short)(p1[r].y & 0xffffu));
                dp += qpv[1][3] * bf2f((unsigned short)(p1[r].y >> 16));
                dp += qpv[2][0] * bf2f((unsigned short)(p2[r].x & 0xffffu));
                dp += qpv[2][1] * bf2f((unsigned short)(p2[r].x >> 16));
                dp += qpv[2][2] * bf2f((unsigned short)(p2[r].y & 0xffffu));
                dp += qpv[2][3] * bf2f((unsigned short)(p2[r].y >> 16));
                float ptt = cpt_r * (q2_r + K2r[r] - 2.f * dp);
                float lg = c_qk * qk + ptt + 1e5f * (ulr_i * ulra[j0 + jl] - 1.f)
                         + c_b * d[r] + cbb_r;
                L[jl * 17 + lcol] = lg;
            }
        }
        __syncthreads();   // C

        // ---- online softmax update (16 lanes per head) ----
        if (t < 192) {
            int h = t >> 4, u = t & 15;
            float v0 = L[(u * 4 + 0) * 17 + h];
            float v1 = L[(u * 4 + 1) * 17 + h];
            float v2 = L[(u * 4 + 2) * 17 + h];
            float v3 = L[(u * 4 + 3) * 17 + h];
            float mx = fmaxf(fmaxf(v0, v1), fmaxf(v2, v3));
            for (int mk = 1; mk < 16; mk <<= 1) mx = fmaxf(mx, __shfl_xor(mx, mk, 16));
            float mold = m_s[h];
            float mnew = fmaxf(mold, mx);
            float w0 = __expf(v0 - mnew), w1 = __expf(v1 - mnew);
            float w2 = __expf(v2 - mnew), w3 = __expf(v3 - mnew);
            Pt[h * 68 + u * 4 + 0] = w0;
            Pt[h * 68 + u * 4 + 1] = w1;
            Pt[h * 68 + u * 4 + 2] = w2;
            Pt[h * 68 + u * 4 + 3] = w3;
            float sm = w0 + w1 + w2 + w3;
            for (int mk = 1; mk < 16; mk <<= 1) sm += __shfl_xor(sm, mk, 16);
            if (u == 0) {
                float al = __expf(mold - mnew);
                m_s[h] = mnew; alph_s[h] = al;
                l_s[h] = l_s[h] * al + sm;
            }
        }
        __syncthreads();   // D

        // ---- o_pair MFMA: D[h][c] += P(16x64) @ z(64x128) ----
        {
            float al[4];
            #pragma unroll
            for (int r = 0; r < 4; ++r) al[r] = alph_s[quad * 4 + r];
            #pragma unroll
            for (int nt = 0; nt < 2; ++nt)
                #pragma unroll
                for (int r = 0; r < 4; ++r) acc_op[nt][r] *= al[r];
            #pragma unroll
            for (int kb = 0; kb < 2; ++kb) {
                f32x4 pa = *(const f32x4*)&Pt[lcol * 68 + kb * 32 + quad * 8];
                f32x4 pb = *(const f32x4*)&Pt[lcol * 68 + kb * 32 + quad * 8 + 4];
                union { s16x8 v; unsigned u[4]; } af;
                af.u[0] = packbf2(pa[0], pa[1]);
                af.u[1] = packbf2(pa[2], pa[3]);
                af.u[2] = packbf2(pb[0], pb[1]);
                af.u[3] = packbf2(pb[2], pb[3]);
                #pragma unroll
                for (int nt = 0; nt < 2; ++nt) {
                    int c = wv * 32 + nt * 16 + lcol;
                    int csw = ((c >> 3) ^ quad) * 8 + (c & 7);
                    s16x8 bfg;
                    #pragma unroll
                    for (int j = 0; j < 8; ++j)
                        bfg[j] = zb[(kb * 32 + quad * 8 + j) * 136 + csw];
                    acc_op[nt] = __builtin_amdgcn_mfma_f32_16x16x32_bf16(af.v, bfg, acc_op[nt], 0, 0, 0);
                }
            }
        }
        // ---- scalar o / o_pt (v, v_pts from L2) ----
        if (vu >= 0) {
            float alpha = alph_s[vrole];
            f32x4 a = acc_s;
            a[0] *= alpha; a[1] *= alpha; a[2] *= alpha; a[3] *= alpha;
            const float* prow = &Pt[vrole * 68 + vhalf * 32];
            const unsigned int* src = vsrc + (size_t)(j0 + vhalf * 32) * vstride + voff;
            #pragma unroll 4
            for (int jj = 0; jj < 32; jj += 4) {
                f32x4 p = *(const f32x4*)(prow + jj);
                #pragma unroll
                for (int m = 0; m < 4; ++m) {
                    uint2 w = *(const uint2*)(src + (size_t)(jj + m) * vstride);
                    float pm = p[m];
                    a[0] += pm * bf2f((unsigned short)(w.x & 0xffffu));
                    a[1] += pm * bf2f((unsigned short)(w.x >> 16));
                    a[2] += pm * bf2f((unsigned short)(w.y & 0xffffu));
                    a[3] += pm * bf2f((unsigned short)(w.y >> 16));
                }
            }
            acc_s = a;
        }
    }

    // ------------------------------ epilogue -------------------------------
    __syncthreads();
    if (t < 16) linv_s[t] = (t < 12) ? 1.f / l_s[t] : 0.f;
    float* vbuf = L;    // safe: no more L readers
    if (vu >= 0) {
        #pragma unroll
        for (int m = 0; m < 4; ++m) vbuf[(vu * 2 + vhalf) * 4 + m] = acc_s[m];
    }
    __syncthreads();
    unsigned short* crow = cat + (size_t)i * 2112;
    if (t < 120) {   // combine value halves
        int role = (t < 48) ? (t >> 2) : (t - 48) / 6;
        float li = linv_s[role];
        float f[4];
        #pragma unroll
        for (int m = 0; m < 4; ++m)
            f[m] = (vbuf[(t * 2) * 4 + m] + vbuf[(t * 2 + 1) * 4 + m]) * li;
        if (t < 48) {
            #pragma unroll
            for (int m = 0; m < 4; ++m) crow[t * 4 + m] = f2bf(f[m]);
        } else {
            int e0 = (t - 48) * 4;
            optb[e0 + 0] = f[0]; optb[e0 + 1] = f[1];
            optb[e0 + 2] = f[2]; optb[e0 + 3] = f[3];
        }
    }
    {
        #pragma unroll
        for (int nt = 0; nt < 2; ++nt)
            #pragma unroll
            for (int r = 0; r < 4; ++r) {
                int h = quad * 4 + r;
                if (h < 12)
                    crow[576 + h * 128 + wv * 32 + nt * 16 + lcol] = f2bf(acc_op[nt][r] * linv_s[h]);
            }
    }
    __syncthreads();
    if (t < 96) {   // invert frame 0, write o_pt xyz + norm
        int hp = t;
        const float* rot = r_rot + (size_t)i * 45;
        float d0 = optb[hp * 3 + 0] - r_trans[(size_t)i * 15 + 0];
        float d1 = optb[hp * 3 + 1] - r_trans[(size_t)i * 15 + 1];
        float d2 = optb[hp * 3 + 2] - r_trans[(size_t)i * 15 + 2];
        float f0 = rot[0] * d0 + rot[3] * d1 + rot[6] * d2;
        float f1 = rot[1] * d0 + rot[4] * d1 + rot[7] * d2;
        float f2 = rot[2] * d0 + rot[5] * d1 + rot[8] * d2;
        crow[192 + hp] = f2bf(f0);
        crow[288 + hp] = f2bf(f1);
        crow[384 + hp] = f2bf(f2);
        crow[480 + hp] = f2bf(sqrtf(f0 * f0 + f1 * f1 + f2 * f2 + 1e-8f));
    }
}

// ------------------------------- K5: reduce split-K parts + bias -----------
__global__ __launch_bounds__(256) void k_out_red(
    const float* __restrict__ parts, const float* __restrict__ bout,
    float* __restrict__ out)
{
    const int x = blockIdx.x * 256 + threadIdx.x;   // < 294912
    float s = bout[x % 384];
    #pragma unroll
    for (int p = 0; p < 6; ++p) s += parts[(size_t)p * 294912 + x];
    out[x] = s;
}

// ------------------------------- launch ------------------------------------
extern "C" void kernel_launch(void* const* d_in, const int* in_sizes, int n_in,
                              void* d_out, int out_size, void* d_ws, size_t ws_size,
                              hipStream_t stream)
{
    const float* s       = (const float*)d_in[0];
    const float* z       = (const float*)d_in[1];
    const float* r_rot   = (const float*)d_in[2];
    const float* r_trans = (const float*)d_in[3];
    const float* mask    = (const float*)d_in[4];
    const float* wq      = (const float*)d_in[5];
    const float* bq      = (const float*)d_in[6];
    const float* wkv     = (const float*)d_in[7];
    const float* bkv     = (const float*)d_in[8];
    const float* wqp     = (const float*)d_in[9];
    const float* bqp     = (const float*)d_in[10];
    const float* wkvp    = (const float*)d_in[11];
    const float* bkvp    = (const float*)d_in[12];
    const float* wb      = (const float*)d_in[13];
    const float* bb      = (const float*)d_in[14];
    const float* head_w  = (const float*)d_in[15];
    const float* wout    = (const float*)d_in[16];
    const float* bout    = (const float*)d_in[17];
    const float* wexp    = (const float*)d_in[18];
    const float* bexp    = (const float*)d_in[19];
    const float* ln_g    = (const float*)d_in[20];
    const float* ln_b    = (const float*)d_in[21];
    // d_in[22]=ww, d_in[23]=bw unused: softmax over size-1 axis == 1.0

    float* wsf = (float*)d_ws;
    float* se_raw = wsf;                  // 294912
    float* lin    = wsf + 294912;         // 884736
    float* qf     = wsf + 1179648;        // 147456
    float* qpf    = wsf + 1327104;        // 110592
    float* k2w    = wsf + 1437696;        // 9216
    float* bcat   = wsf + 1446912;        // 1152
    float* parts  = wsf + 1448064;        // 1769472 (6 x 294912)
    unsigned short* ub = (unsigned short*)(wsf + 3217536);
    unsigned short* s_bf   = ub;              // 294912
    unsigned short* we_bf  = ub + 294912;     // 147456
    unsigned short* wc_bf  = ub + 442368;     // 442368
    unsigned short* wo_bf  = ub + 884736;     // 811008
    unsigned short* se0_bf = ub + 1695744;    // 294912
    unsigned short* kbf    = ub + 1990656;    // 147456
    unsigned short* vbf    = ub + 2138112;    // 147456
    unsigned short* kpbf   = ub + 2285568;    // 110592
    unsigned short* vpbf   = ub + 2396160;    // 221184
    unsigned short* cat_bf = ub + 2617344;    // 1622016
    float* out = (float*)d_out;

    k_prep<<<6629, 256, 0, stream>>>(s, wexp, wq, wkv, wqp, wkvp, wout,
                                     bq, bkv, bqp, bkvp,
                                     s_bf, we_bf, wc_bf, wo_bf, bcat);
    k_mm<<<dim3(12, 6, 1), 256, 0, stream>>>(s_bf, 384, we_bf, 384,
                                             se_raw, 384, bexp, 12, 0);
    k_ln<<<192, 256, 0, stream>>>(se_raw, ln_g, ln_b, se0_bf);
    k_mm<<<dim3(12, 18, 1), 256, 0, stream>>>(se0_bf, 384, wc_bf, 384,
                                              lin, 1152, bcat, 12, 0);
    k_post<<<96, 256, 0, stream>>>(lin, r_rot, r_trans,
                                   qf, kbf, vbf, qpf, kpbf, vpbf, k2w);
    k_attn<<<768, 256, 0, stream>>>(z, mask, head_w, wb, bb, r_rot, r_trans,
                                    qf, qpf, k2w, kbf, vbf, kpbf, vpbf, cat_bf);
    k_mm<<<dim3(12, 6, 6), 256, 0, stream>>>(cat_bf, 2112, wo_bf, 2112,
                                             parts, 384, nullptr, 11, 294912);
    k_out_red<<<1152, 256, 0, stream>>>(parts, bout, out);
}